// Round 6
// baseline (408.670 us; speedup 1.0000x reference)
//
#include <hip/hip_runtime.h>
#include <math.h>

#define N 512
#define H 128
#define L 4
#define NUM_RBF 50
#define NMOL 16
#define QSPL 4            // i-range splits per j in k_msg

typedef __attribute__((ext_vector_type(8))) short short8;
typedef __attribute__((ext_vector_type(4))) float float4v;

__device__ __forceinline__ float silu_f(float v) {
    return v / (1.0f + __expf(-v));
}

__device__ __forceinline__ unsigned short f2bf(float f) {
    unsigned int u = __float_as_uint(f);
    unsigned int r = (u + 0x7FFFu + ((u >> 16) & 1u)) >> 16;  // RNE
    return (unsigned short)r;
}

// x[i,h] = embed[clip(an[i])]; a[i,h] = b1[h] + x[i,:] @ Wx[:,h]; zero msum/cnt.
__global__ __launch_bounds__(H) void k_embed_lin(const int* __restrict__ an,
                                                 const float* __restrict__ embed,
                                                 const float* __restrict__ wx,
                                                 const float* __restrict__ b1,
                                                 float* __restrict__ x,
                                                 float* __restrict__ a,
                                                 float* __restrict__ msum,
                                                 int* __restrict__ cnt) {
    int i = blockIdx.x, h = threadIdx.x;
    __shared__ float xs[H];
    msum[i * H + h] = 0.0f;
    if (h == 0) cnt[i] = 0;
    int z = an[i];
    z = min(max(z, 0), 99);
    float xv = embed[z * H + h];
    x[i * H + h] = xv;
    xs[h] = xv;
    __syncthreads();
    float a0 = b1[h], a1 = 0.f, a2 = 0.f, a3 = 0.f;
#pragma unroll 8
    for (int k = 0; k < H; k += 4) {
        a0 += xs[k]     * wx[(k)     * H + h];
        a1 += xs[k + 1] * wx[(k + 1) * H + h];
        a2 += xs[k + 2] * wx[(k + 2) * H + h];
        a3 += xs[k + 3] * wx[(k + 3) * H + h];
    }
    a[i * H + h] = (a0 + a1) + (a2 + a3);
}

// Barrier-free, LDS-free MFMA message kernel. Block = (j, i-quarter), grid QSPL*N,
// 256 threads = 4 waves. Wave wv owns i-tiles {wv*2, wv*2+1} of its quarter and ALL
// 128 h (8 h-tiles of B-frags in registers). Each lane computes its own A-fragment
// features in registers (lane nn -> row i=ibase+nn, quad -> k-strip). Output summed
// into msum[j*H+h] via float atomicAdd (zeroed by k_embed_lin / k_update).
__global__ __launch_bounds__(256) void k_msg(const float* __restrict__ a,
                                             const float* __restrict__ pos,
                                             const float* __restrict__ wfeat,
                                             float* __restrict__ msum,
                                             int* __restrict__ cnt) {
    int bx = blockIdx.x;
    int j = bx >> 2;
    int q = bx & (QSPL - 1);
    int tid = threadIdx.x;
    int lane = tid & 63;
    int wv = tid >> 6;        // wave 0..3
    int nn = lane & 15;       // tile row (A) / output col group
    int quad = lane >> 4;     // 0..3

    // B fragments, loop-invariant: B[k = 32c + quad*8+jj][h = ht*16 + nn]
    short8 bfrag[2][8];
#pragma unroll
    for (int ht = 0; ht < 8; ht++) {
        int h = ht * 16 + nn;
#pragma unroll
        for (int c = 0; c < 2; c++) {
            short8 b;
#pragma unroll
            for (int jj = 0; jj < 8; jj++) {
                int k = c * 32 + quad * 8 + jj;
                float v = (k < NUM_RBF + 3) ? wfeat[k * H + h] : 0.0f;
                b[jj] = (short)f2bf(v);
            }
            bfrag[c][ht] = b;
        }
    }

    float pjx = pos[j * 3 + 0], pjy = pos[j * 3 + 1], pjz = pos[j * 3 + 2];
    const float DELTA = 5.0f / 49.0f;

    float ph[8];
#pragma unroll
    for (int ht = 0; ht < 8; ht++) ph[ht] = 0.0f;
    float cl = 0.0f;

#pragma unroll
    for (int t = 0; t < 2; t++) {
        int ibase = q * 128 + wv * 32 + t * 16;
        int i = ibase + nn;
        float dx = pos[i * 3 + 0] - pjx;
        float dy = pos[i * 3 + 1] - pjy;
        float dz = pos[i * 3 + 2] - pjz;
        float d = sqrtf(dx * dx + dy * dy + dz * dz);
        float rinv = 1.0f / fmaxf(d, 1e-8f);
        float vf = (float)((d < 5.0f) && (i != j));

        // A fragments in registers: lane holds feats of row i, k = quad*8+jj (+32)
        short8 af0, af1;
#pragma unroll
        for (int jj = 0; jj < 8; jj++) {
            int k0 = quad * 8 + jj;               // 0..31: always RBF
            float t0 = d - (float)k0 * DELTA;
            af0[jj] = (short)f2bf(__expf(-50.0f * t0 * t0));
            int k1 = 32 + quad * 8 + jj;          // 32..63
            float v1;
            if (k1 < NUM_RBF) {
                float t1 = d - (float)k1 * DELTA;
                v1 = __expf(-50.0f * t1 * t1);
            } else if (k1 == NUM_RBF)     v1 = dx * rinv;
            else if (k1 == NUM_RBF + 1)   v1 = dy * rinv;
            else if (k1 == NUM_RBF + 2)   v1 = dz * rinv;
            else                          v1 = 0.0f;
            af1[jj] = (short)f2bf(v1);
        }

        // valid mask for this lane's 4 output rows (i = ibase + quad*4 + r):
        // source lane quad*4+r (in first 16 lanes) computed vf for that i.
        float vmr[4];
#pragma unroll
        for (int r = 0; r < 4; r++) vmr[r] = __shfl(vf, quad * 4 + r, 64);

        // per-tile valid count (each quad's rows counted once; reduce over quads)
        float s = (vmr[0] + vmr[1]) + (vmr[2] + vmr[3]);
        s += __shfl_xor(s, 16, 64);
        s += __shfl_xor(s, 32, 64);
        cl += s;   // only lane 0's value is used

#pragma unroll
        for (int ht = 0; ht < 8; ht++) {
            float4v acc = {0.0f, 0.0f, 0.0f, 0.0f};
            acc = __builtin_amdgcn_mfma_f32_16x16x32_bf16(af0, bfrag[0][ht], acc, 0, 0, 0);
            acc = __builtin_amdgcn_mfma_f32_16x16x32_bf16(af1, bfrag[1][ht], acc, 0, 0, 0);
#pragma unroll
            for (int r = 0; r < 4; r++) {
                float av = a[(ibase + quad * 4 + r) * H + ht * 16 + nn];
                ph[ht] += vmr[r] * silu_f(acc[r] + av);
            }
        }
    }

    // reduce each h-partial over quads; lanes 0..15 hold h = ht*16 + lane
#pragma unroll
    for (int ht = 0; ht < 8; ht++) {
        float v = ph[ht];
        v += __shfl_xor(v, 16, 64);
        v += __shfl_xor(v, 32, 64);
        if (lane < 16) atomicAdd(&msum[j * H + ht * 16 + lane], v);
    }
    if (lane == 0) atomicAdd(&cnt[j], (int)(cl + 0.5f));
}

// 4-way split-K update: 512 threads = 4 groups of 128. Also re-zeroes msum/cnt
// for the next layer's atomic accumulation.
__global__ __launch_bounds__(512) void k_update(float* __restrict__ msum,
                                                int* __restrict__ cnt,
                                                const float* __restrict__ w2,
                                                const float* __restrict__ b2,
                                                const float* __restrict__ u1,
                                                const float* __restrict__ ub1,
                                                const float* __restrict__ u2,
                                                const float* __restrict__ ub2,
                                                float* __restrict__ x,
                                                const float* __restrict__ wxn,
                                                const float* __restrict__ b1n,
                                                float* __restrict__ a_next) {
    int j = blockIdx.x;
    int h = threadIdx.x & 127;
    int grp = threadIdx.x >> 7;   // 0..3

    __shared__ float sj[H], xj[H], ag[H], hid[H], xn[H];
    __shared__ float part[4][H];

    if (grp == 0) {
        xj[h] = x[j * H + h];
    } else if (grp == 1) {
        sj[h] = msum[j * H + h];
    }
    int c = cnt[j];
    __syncthreads();

    // re-zero for next layer (reads above are done)
    if (grp == 3) {
        msum[j * H + h] = 0.0f;
        if (h == 0) cnt[j] = 0;
    }

    {
        float p0 = 0.f, p1 = 0.f, p2 = 0.f, p3 = 0.f;
        int k0 = grp * 32;
#pragma unroll 8
        for (int k = 0; k < 32; k += 4) {
            p0 += sj[k0 + k]     * w2[(k0 + k)     * H + h];
            p1 += sj[k0 + k + 1] * w2[(k0 + k + 1) * H + h];
            p2 += sj[k0 + k + 2] * w2[(k0 + k + 2) * H + h];
            p3 += sj[k0 + k + 3] * w2[(k0 + k + 3) * H + h];
        }
        part[grp][h] = (p0 + p1) + (p2 + p3);
    }
    __syncthreads();
    if (grp == 0) ag[h] = part[0][h] + part[1][h] + part[2][h] + part[3][h] + (float)c * b2[h];
    __syncthreads();

    {
        const float* src = (grp < 2) ? xj : ag;
        int sbase = (grp & 1) * 64;
        int k0 = grp * 64;
        float p0 = 0.f, p1 = 0.f, p2 = 0.f, p3 = 0.f;
#pragma unroll 8
        for (int k = 0; k < 64; k += 4) {
            p0 += src[sbase + k]     * u1[(k0 + k)     * H + h];
            p1 += src[sbase + k + 1] * u1[(k0 + k + 1) * H + h];
            p2 += src[sbase + k + 2] * u1[(k0 + k + 2) * H + h];
            p3 += src[sbase + k + 3] * u1[(k0 + k + 3) * H + h];
        }
        part[grp][h] = (p0 + p1) + (p2 + p3);
    }
    __syncthreads();
    if (grp == 0) hid[h] = silu_f(part[0][h] + part[1][h] + part[2][h] + part[3][h] + ub1[h]);
    __syncthreads();

    {
        float p0 = 0.f, p1 = 0.f, p2 = 0.f, p3 = 0.f;
        int k0 = grp * 32;
#pragma unroll 8
        for (int k = 0; k < 32; k += 4) {
            p0 += hid[k0 + k]     * u2[(k0 + k)     * H + h];
            p1 += hid[k0 + k + 1] * u2[(k0 + k + 1) * H + h];
            p2 += hid[k0 + k + 2] * u2[(k0 + k + 2) * H + h];
            p3 += hid[k0 + k + 3] * u2[(k0 + k + 3) * H + h];
        }
        part[grp][h] = (p0 + p1) + (p2 + p3);
    }
    __syncthreads();
    if (grp == 0) {
        float xv = xj[h] + part[0][h] + part[1][h] + part[2][h] + part[3][h] + ub2[h];
        x[j * H + h] = xv;
        xn[h] = xv;
    }

    if (a_next != nullptr) {
        __syncthreads();
        float p0 = 0.f, p1 = 0.f, p2 = 0.f, p3 = 0.f;
        int k0 = grp * 32;
#pragma unroll 8
        for (int k = 0; k < 32; k += 4) {
            p0 += xn[k0 + k]     * wxn[(k0 + k)     * H + h];
            p1 += xn[k0 + k + 1] * wxn[(k0 + k + 1) * H + h];
            p2 += xn[k0 + k + 2] * wxn[(k0 + k + 2) * H + h];
            p3 += xn[k0 + k + 3] * wxn[(k0 + k + 3) * H + h];
        }
        part[grp][h] = (p0 + p1) + (p2 + p3);
        __syncthreads();
        if (grp == 0)
            a_next[j * H + h] = part[0][h] + part[1][h] + part[2][h] + part[3][h] + b1n[h];
    }
}

// per-molecule mean pool + 2-layer output MLP. 256 threads = 2 i-halves.
__global__ __launch_bounds__(256) void k_pool(const float* __restrict__ x,
                                              const int* __restrict__ batch,
                                              const float* __restrict__ ow1,
                                              const float* __restrict__ ob1,
                                              const float* __restrict__ ow2,
                                              const float* __restrict__ ob2,
                                              float* __restrict__ out) {
    int m = blockIdx.x;
    int h = threadIdx.x & 127;
    int half = threadIdx.x >> 7;
    __shared__ float sp[2][H];
    __shared__ int cp[2];
    __shared__ float pooled[H];
    __shared__ float hid[H / 2];

    float s = 0.0f;
    int cntm = 0;
    for (int i = half * (N / 2); i < (half + 1) * (N / 2); i++) {
        if (batch[i] == m) { s += x[i * H + h]; cntm++; }
    }
    sp[half][h] = s;
    if (h == 0) cp[half] = cntm;
    __syncthreads();

    if (half == 0) pooled[h] = (sp[0][h] + sp[1][h]) / (float)max(cp[0] + cp[1], 1);
    __syncthreads();

    if (half == 0 && h < H / 2) {
        float p0 = 0.f, p1 = 0.f;
        for (int k = 0; k < H; k += 2) {
            p0 += pooled[k]     * ow1[(k)     * (H / 2) + h];
            p1 += pooled[k + 1] * ow1[(k + 1) * (H / 2) + h];
        }
        hid[h] = silu_f(p0 + p1 + ob1[h]);
    }
    __syncthreads();

    if (threadIdx.x == 0) {
        float o = ob2[0];
        for (int k = 0; k < H / 2; k++) o += hid[k] * ow2[k];
        out[m] = o;
    }
}

extern "C" void kernel_launch(void* const* d_in, const int* in_sizes, int n_in,
                              void* d_out, int out_size, void* d_ws, size_t ws_size,
                              hipStream_t stream) {
    const int*   an      = (const int*)d_in[0];
    const float* pos     = (const float*)d_in[1];
    const int*   batch   = (const int*)d_in[2];
    const float* embed   = (const float*)d_in[3];
    const float* msg_w1  = (const float*)d_in[4];   // L x 181 x 128
    const float* msg_b1  = (const float*)d_in[5];
    const float* msg_w2  = (const float*)d_in[6];   // L x 128 x 128
    const float* msg_b2  = (const float*)d_in[7];
    const float* upd_w1  = (const float*)d_in[8];   // L x 256 x 128
    const float* upd_b1  = (const float*)d_in[9];
    const float* upd_w2  = (const float*)d_in[10];  // L x 128 x 128
    const float* upd_b2  = (const float*)d_in[11];
    const float* out_w1  = (const float*)d_in[12];  // 128 x 64
    const float* out_b1  = (const float*)d_in[13];
    const float* out_w2  = (const float*)d_in[14];  // 64 x 1
    const float* out_b2  = (const float*)d_in[15];
    float* out = (float*)d_out;

    float* x    = (float*)d_ws;        // N*H
    float* a    = x + N * H;           // N*H
    float* msum = a + N * H;           // N*H
    int*   cnt  = (int*)(msum + N * H);// N

    const int W1ROWS = H + NUM_RBF + 3;  // 181

    k_embed_lin<<<N, H, 0, stream>>>(an, embed, msg_w1, msg_b1, x, a, msum, cnt);
    for (int l = 0; l < L; l++) {
        k_msg<<<QSPL * N, 256, 0, stream>>>(a, pos, msg_w1 + l * W1ROWS * H + H * H,
                                            msum, cnt);
        const float* wxn = (l + 1 < L) ? (msg_w1 + (l + 1) * W1ROWS * H) : nullptr;
        const float* b1n = (l + 1 < L) ? (msg_b1 + (l + 1) * H) : nullptr;
        float* an_ = (l + 1 < L) ? a : nullptr;
        k_update<<<N, 512, 0, stream>>>(msum, cnt,
                                        msg_w2 + l * H * H, msg_b2 + l * H,
                                        upd_w1 + l * 2 * H * H, upd_b1 + l * H,
                                        upd_w2 + l * H * H, upd_b2 + l * H, x,
                                        wxn, b1n, an_);
    }
    k_pool<<<NMOL, 256, 0, stream>>>(x, batch, out_w1, out_b1, out_w2, out_b2, out);
}